// Round 1
// 3028.968 us; speedup vs baseline: 1.0397x; 1.0397x over previous
//
#include <hip/hip_runtime.h>

typedef unsigned short u16;
typedef __bf16 bf16x8 __attribute__((ext_vector_type(8)));
typedef float f32x4 __attribute__((ext_vector_type(4)));

__device__ __forceinline__ float b2f(u16 u) {
  union { unsigned int i; float f; } x; x.i = ((unsigned int)u) << 16; return x.f;
}
__device__ __forceinline__ u16 f2b(float f) {
  union { float f; unsigned int i; } x; x.f = f;
  unsigned int r = (x.i + 0x7fffu + ((x.i >> 16) & 1u)) >> 16;
  return (u16)r;
}

__device__ __forceinline__ void async16(const void* g, void* l) {
  __builtin_amdgcn_global_load_lds((const __attribute__((address_space(1))) void*)g,
                                   (__attribute__((address_space(3))) void*)l, 16, 0, 0);
}

// Epilogue modes
#define EPI_BF16    0   // store bf16(v)
#define EPI_SILU    1   // store bf16(silu(v))
#define EPI_SIGMOID 2   // store bf16(sigmoid(v))
#define EPI_ROUTED  3   // f32 C [+]= rowscale[row*3+rs_off]*v
#define EPI_FINAL   4   // f32 C = X + G*v  (X f32, G bf16)
#define EPI_F32SC   5   // store f32 v*scale
// v = acc + bias[col] + bcast[(row>>11)*ldbc + col]

// C[M,N] = A[M,K] @ Bt[N,K]^T ; 128x128 tile, BK=32, 4 waves (2x2), 4x4 MFMA tiles/wave
// Double-buffered LDS: prefetch next K-step's tiles while computing current one.
__global__ __launch_bounds__(256) void gemm_bt(
    const u16* __restrict__ A, int lda, long long sA,
    const u16* __restrict__ B, int ldb, long long sB,
    const float* __restrict__ bias,
    const float* __restrict__ bcast, int ldbc,
    void* __restrict__ Cv, int ldc, long long sC,
    int M, int N, int K,
    int epi, float scale,
    const float* __restrict__ rowscale, int rs_off, int accum,
    const float* __restrict__ Xres, const u16* __restrict__ Gg)
{
  __shared__ u16 As[2][128 * 32];
  __shared__ u16 Bs[2][128 * 32];
  const int z = blockIdx.z;
  A += (long long)z * sA;
  B += (long long)z * sB;
  const int m0 = blockIdx.y * 128, n0 = blockIdx.x * 128;
  const int tid = threadIdx.x;
  const int lane = tid & 63, w = tid >> 6;
  const int wm = w >> 1, wn = w & 1;

  const int sr = lane >> 2;
  const int sc = (lane & 3) * 8;
  int ra0 = m0 + w * 16 + sr;      if (ra0 > M - 1) ra0 = M - 1;
  int ra1 = m0 + 64 + w * 16 + sr; if (ra1 > M - 1) ra1 = M - 1;
  int rb0 = n0 + w * 16 + sr;      if (rb0 > N - 1) rb0 = N - 1;
  int rb1 = n0 + 64 + w * 16 + sr; if (rb1 > N - 1) rb1 = N - 1;
  const u16* pa0 = A + (long long)ra0 * lda + sc;
  const u16* pa1 = A + (long long)ra1 * lda + sc;
  const u16* pb0 = B + (long long)rb0 * ldb + sc;
  const u16* pb1 = B + (long long)rb1 * ldb + sc;
  const int lw = w * 512;   // wave-uniform LDS chunk offset (u16 units)

  f32x4 acc[4][4] = {};

  const int kch = (lane >> 4) * 8;
  const int rr = lane & 15;

  // prologue: stage K-step 0 into buffer 0
  async16(pa0, &As[0][lw]);
  async16(pa1, &As[0][2048 + lw]);
  async16(pb0, &Bs[0][lw]);
  async16(pb1, &Bs[0][2048 + lw]);

  int cur = 0;
  for (int k0 = 0; k0 < K; k0 += 32) {
    // barrier: (a) drains vmcnt -> buf[cur] staged; (b) all waves done reading buf[cur^1]
    __syncthreads();
    const int kn = k0 + 32;
    if (kn < K) {
      const int nb = cur ^ 1;
      // issue next tile's loads NOW; they fly under the MFMAs below and are
      // drained by the next iteration's barrier (implicit vmcnt(0)).
      async16(pa0 + kn, &As[nb][lw]);
      async16(pa1 + kn, &As[nb][2048 + lw]);
      async16(pb0 + kn, &Bs[nb][lw]);
      async16(pb1 + kn, &Bs[nb][2048 + lw]);
    }
    bf16x8 af[4], bfr[4];
#pragma unroll
    for (int mi = 0; mi < 4; ++mi)
      af[mi] = *(const bf16x8*)(&As[cur][(wm * 64 + mi * 16 + rr) * 32 + kch]);
#pragma unroll
    for (int ni = 0; ni < 4; ++ni)
      bfr[ni] = *(const bf16x8*)(&Bs[cur][(wn * 64 + ni * 16 + rr) * 32 + kch]);
#pragma unroll
    for (int mi = 0; mi < 4; ++mi)
#pragma unroll
      for (int ni = 0; ni < 4; ++ni)
        acc[mi][ni] = __builtin_amdgcn_mfma_f32_16x16x32_bf16(af[mi], bfr[ni], acc[mi][ni], 0, 0, 0);
    cur ^= 1;
  }

  u16* Cb = (u16*)Cv;
  float* Cf = (float*)Cv;
#pragma unroll
  for (int ni = 0; ni < 4; ++ni) {
    int col = n0 + wn * 64 + ni * 16 + (lane & 15);
    if (col >= N) continue;
    float bv = bias ? bias[col] : 0.0f;
#pragma unroll
    for (int mi = 0; mi < 4; ++mi) {
#pragma unroll
      for (int r = 0; r < 4; ++r) {
        int row = m0 + wm * 64 + mi * 16 + (lane >> 4) * 4 + r;
        if (row >= M) continue;
        float v = acc[mi][ni][r] + bv;
        if (bcast) v += bcast[(row >> 11) * ldbc + col];
        long long cidx = (long long)z * sC + (long long)row * ldc + col;
        if (epi == EPI_BF16) {
          Cb[cidx] = f2b(v);
        } else if (epi == EPI_SILU) {
          Cb[cidx] = f2b(v / (1.0f + __expf(-v)));
        } else if (epi == EPI_SIGMOID) {
          Cb[cidx] = f2b(1.0f / (1.0f + __expf(-v)));
        } else if (epi == EPI_ROUTED) {
          float rs = rowscale[row * 3 + rs_off];
          if (accum) Cf[cidx] += rs * v; else Cf[cidx] = rs * v;
        } else if (epi == EPI_FINAL) {
          long long xi = (long long)row * ldc + col;
          Cf[cidx] = Xres[xi] + b2f(Gg[xi]) * v;
        } else { // EPI_F32SC
          Cf[cidx] = v * scale;
        }
      }
    }
  }
}

// out[c][r] = bf16(in[r][c]); reads first R rows of f32 in (row stride C). dims multiples of 32.
__global__ __launch_bounds__(256) void transpose_cvt(const float* __restrict__ in, u16* __restrict__ out, int R, int C) {
  __shared__ float tile[32][33];
  int c0 = blockIdx.x * 32, r0 = blockIdx.y * 32;
  int tx = threadIdx.x & 31, ty = threadIdx.x >> 5;
#pragma unroll
  for (int i = 0; i < 4; ++i) {
    int r = ty + i * 8;
    tile[r][tx] = in[(long long)(r0 + r) * C + c0 + tx];
  }
  __syncthreads();
#pragma unroll
  for (int i = 0; i < 4; ++i) {
    int r = ty + i * 8;
    out[(long long)(c0 + r) * R + r0 + tx] = f2b(tile[tx][r]);
  }
}

__global__ __launch_bounds__(256) void cvt_bf16(const float* __restrict__ in, u16* __restrict__ out, int n) {
  for (int i = blockIdx.x * 256 + threadIdx.x; i < n; i += gridDim.x * 256)
    out[i] = f2b(in[i]);
}

// LayerNorm over H=1024 (f32 in); writes bf16 nx into ne[:, 0:1024] (row stride 2048)
__global__ __launch_bounds__(256) void ln_kernel(const float* __restrict__ x, const float* __restrict__ gamma,
                                                 const float* __restrict__ beta, u16* __restrict__ ne) {
  int t = blockIdx.x;
  int tid = threadIdx.x;
  const float* xr = x + (long long)t * 1024;
  float v[4];
  float s = 0.f, sq = 0.f;
#pragma unroll
  for (int i = 0; i < 4; ++i) {
    v[i] = xr[tid * 4 + i];
    s += v[i]; sq += v[i] * v[i];
  }
#pragma unroll
  for (int d = 32; d; d >>= 1) { s += __shfl_xor(s, d, 64); sq += __shfl_xor(sq, d, 64); }
  __shared__ float ls[4], lq[4];
  int w = tid >> 6, lane = tid & 63;
  if (lane == 0) { ls[w] = s; lq[w] = sq; }
  __syncthreads();
  s = ls[0] + ls[1] + ls[2] + ls[3];
  sq = lq[0] + lq[1] + lq[2] + lq[3];
  float mean = s * (1.0f / 1024.0f);
  float var = sq * (1.0f / 1024.0f) - mean * mean;
  float rstd = rsqrtf(var + 1e-5f);
  long long base = (long long)t * 2048;
#pragma unroll
  for (int i = 0; i < 4; ++i) {
    int c = tid * 4 + i;
    ne[base + c] = f2b((v[i] - mean) * rstd * gamma[c] + beta[c]);
  }
}

// bc[b][n] = sum_k anchor[b,k] * W[(2048+k)*ldw + n], k<1024, b<8  (all f32)
__global__ __launch_bounds__(256) void anchor_term(const float* __restrict__ anchor, const float* __restrict__ W,
                                                   int ldw, int N, float* __restrict__ bc) {
  int n = blockIdx.x * 256 + threadIdx.x;
  if (n >= N) return;
  float acc[8] = {};
  for (int k = 0; k < 1024; ++k) {
    float wv = W[(long long)(2048 + k) * ldw + n];
#pragma unroll
    for (int b = 0; b < 8; ++b) acc[b] += anchor[b * 1024 + k] * wv;
  }
#pragma unroll
  for (int b = 0; b < 8; ++b) bc[b * N + n] = acc[b];
}

// softmax over P=64 scores per token; one wave per token
__global__ __launch_bounds__(256) void attn_softmax(const float* __restrict__ scores, u16* __restrict__ weights) {
  int gid = blockIdx.x * 256 + threadIdx.x;
  int t = gid >> 6, lane = gid & 63;
  float sv = scores[(long long)t * 64 + lane];
  float m = sv;
#pragma unroll
  for (int d = 32; d; d >>= 1) m = fmaxf(m, __shfl_xor(m, d, 64));
  float e = __expf(sv - m);
  float sum = e;
#pragma unroll
  for (int d = 32; d; d >>= 1) sum += __shfl_xor(sum, d, 64);
  weights[(long long)t * 64 + lane] = f2b(e / sum);
}

// router: logits[e] = ne[t,:]@rW[0:2048,e] + anchor[b,:]@rW[2048:3072,e] + rb[e]; softmax E=3
__global__ __launch_bounds__(256) void router_kernel(const u16* __restrict__ ne, const float* __restrict__ anchor,
                                                     const float* __restrict__ rW, const float* __restrict__ rb,
                                                     float* __restrict__ probs) {
  int gid = blockIdx.x * 256 + threadIdx.x;
  int t = gid >> 6, lane = gid & 63;
  int b = t >> 11;
  const u16* cr = ne + (long long)t * 2048;
  const float* ar = anchor + (long long)b * 1024;
  float s0 = 0.f, s1 = 0.f, s2 = 0.f;
  for (int c = lane; c < 2048; c += 64) {
    float xv = b2f(cr[c]);
    s0 += xv * rW[c * 3 + 0];
    s1 += xv * rW[c * 3 + 1];
    s2 += xv * rW[c * 3 + 2];
  }
  for (int c = lane; c < 1024; c += 64) {
    float xv = ar[c];
    s0 += xv * rW[(2048 + c) * 3 + 0];
    s1 += xv * rW[(2048 + c) * 3 + 1];
    s2 += xv * rW[(2048 + c) * 3 + 2];
  }
#pragma unroll
  for (int d = 32; d; d >>= 1) {
    s0 += __shfl_xor(s0, d, 64);
    s1 += __shfl_xor(s1, d, 64);
    s2 += __shfl_xor(s2, d, 64);
  }
  s0 += rb[0]; s1 += rb[1]; s2 += rb[2];
  float m = fmaxf(s0, fmaxf(s1, s2));
  float e0 = __expf(s0 - m), e1 = __expf(s1 - m), e2 = __expf(s2 - m);
  float inv = 1.0f / (e0 + e1 + e2);
  if (lane == 0) {
    probs[(long long)t * 3 + 0] = e0 * inv;
    probs[(long long)t * 3 + 1] = e1 * inv;
    probs[(long long)t * 3 + 2] = e2 * inv;
  }
}

extern "C" void kernel_launch(void* const* d_in, const int* in_sizes, int n_in,
                              void* d_out, int out_size, void* d_ws, size_t ws_size,
                              hipStream_t stream) {
  const float* X      = (const float*)d_in[0];   // [16384,1024]
  const float* anchor = (const float*)d_in[1];   // [8,1024]
  const float* proto  = (const float*)d_in[2];   // [512,1024]
  const float* gamma  = (const float*)d_in[3];
  const float* beta   = (const float*)d_in[4];
  const float* Wq     = (const float*)d_in[5];
  const float* Wk     = (const float*)d_in[6];
  const float* Wv     = (const float*)d_in[7];
  const float* rW     = (const float*)d_in[8];   // [3072,3]
  const float* rb     = (const float*)d_in[9];
  const float* ew1    = (const float*)d_in[10];  // [3,3072,2048]
  const float* eb1    = (const float*)d_in[11];
  const float* ew2    = (const float*)d_in[12];  // [3,2048,1024]
  const float* eb2    = (const float*)d_in[13];
  const float* gw1    = (const float*)d_in[14];  // [3072,1024]
  const float* gb1    = (const float*)d_in[15];
  const float* gw2    = (const float*)d_in[16];  // [1024,1024]
  const float* gb2    = (const float*)d_in[17];
  const float* ow     = (const float*)d_in[18];  // [1024,1024]
  const float* ob     = (const float*)d_in[19];
  float* out = (float*)d_out;

  char* p = (char*)d_ws;
  size_t used = 0;
  auto alloc = [&](size_t bytes) {
    char* r = p; size_t a = (bytes + 255) & ~((size_t)255);
    p += a; used += a; return r;
  };
  u16* ne     = (u16*)alloc(16384ull * 2048 * 2);     // 64 MB [nx | evidence] bf16
  u16* S1     = (u16*)alloc(16384ull * 2048 * 2);     // 64 MB: q -> h -> gh|g -> routed_bf|g
  float* routed = (float*)alloc(16384ull * 1024 * 4); // 64 MB
  u16* w8     = (u16*)alloc(2048ull * 2048 * 2);      // 8 MB weight scratch (bf16)
  u16* proto_bf = (u16*)alloc(512ull * 1024 * 2);     // 1 MB
  u16* kbuf   = (u16*)alloc(512ull * 1024 * 2);
  u16* v_t    = (u16*)alloc(1024ull * 512 * 2);
  u16* wts    = (u16*)alloc(16384ull * 64 * 2);
  float* scores = (float*)alloc(16384ull * 64 * 4);
  float* probs  = (float*)alloc(16384ull * 3 * 4);
  float* anch   = (float*)alloc(8ull * 2048 * 4);
  if (used > ws_size) return;  // clean diagnostic fail instead of GPU fault

  u16* gh = S1;                    // gate hidden [16384,1024]
  u16* g  = S1 + 16384ull * 1024;  // sigmoid gate [16384,1024]
  u16* routed_bf = S1;             // reuses gh region after g is computed

  auto gemm = [&](const u16* A, int lda, long long sA,
                  const u16* B, int ldb, long long sB,
                  const float* bias, const float* bcast, int ldbc,
                  void* C, int ldc, long long sC,
                  int M, int N, int K, int Z,
                  int epi, float scale, const float* rs, int rs_off, int accum,
                  const float* Xr, const u16* Gg) {
    dim3 grd((N + 127) / 128, (M + 127) / 128, Z);
    gemm_bt<<<grd, 256, 0, stream>>>(A, lda, sA, B, ldb, sB, bias, bcast, ldbc,
                                     C, ldc, sC, M, N, K, epi, scale, rs, rs_off, accum, Xr, Gg);
  };

  // ---- phase A: LN + attention ----
  ln_kernel<<<16384, 256, 0, stream>>>(X, gamma, beta, ne);
  cvt_bf16<<<512, 256, 0, stream>>>(proto, proto_bf, 512 * 1024);

  transpose_cvt<<<dim3(32, 32), 256, 0, stream>>>(Wk, w8, 1024, 1024);
  gemm(proto_bf, 1024, 0, w8, 1024, 0, nullptr, nullptr, 0, kbuf, 1024, 0,
       512, 1024, 1024, 1, EPI_BF16, 0.f, nullptr, 0, 0, nullptr, nullptr);

  transpose_cvt<<<dim3(32, 32), 256, 0, stream>>>(Wv, w8, 1024, 1024);
  // v_t[h][bp] = sum_k Wv^T[h][k] * proto[bp][k]
  gemm(w8, 1024, 0, proto_bf, 1024, 0, nullptr, nullptr, 0, v_t, 512, 0,
       1024, 512, 1024, 1, EPI_BF16, 0.f, nullptr, 0, 0, nullptr, nullptr);

  transpose_cvt<<<dim3(32, 32), 256, 0, stream>>>(Wq, w8, 1024, 1024);
  gemm(ne, 2048, 0, w8, 1024, 0, nullptr, nullptr, 0, S1, 1024, 0,   // q
       16384, 1024, 1024, 1, EPI_BF16, 0.f, nullptr, 0, 0, nullptr, nullptr);

  gemm(S1, 1024, 2048ll * 1024, kbuf, 1024, 64ll * 1024, nullptr, nullptr, 0,
       scores, 64, 2048ll * 64, 2048, 64, 1024, 8, EPI_F32SC, 0.03125f, nullptr, 0, 0, nullptr, nullptr);
  attn_softmax<<<4096, 256, 0, stream>>>(scores, wts);
  gemm(wts, 64, 2048ll * 64, v_t, 512, 64, nullptr, nullptr, 0,
       ne + 1024, 2048, 2048ll * 2048, 2048, 1024, 64, 8, EPI_BF16, 0.f, nullptr, 0, 0, nullptr, nullptr);

  // ---- phase B: router ----
  router_kernel<<<4096, 256, 0, stream>>>(ne, anchor, rW, rb, probs);

  // ---- phase C: experts ----
  for (int e = 0; e < 3; ++e) {
    const float* W1 = ew1 + (long long)e * 3072 * 2048;  // [3072,2048]
    const float* W2 = ew2 + (long long)e * 2048 * 1024;  // [2048,1024]
    transpose_cvt<<<dim3(64, 64), 256, 0, stream>>>(W1, w8, 2048, 2048);  // first 2048 rows -> [2048,2048]
    anchor_term<<<8, 256, 0, stream>>>(anchor, W1, 2048, 2048, anch);
    gemm(ne, 2048, 0, w8, 2048, 0, eb1 + e * 2048, anch, 2048, S1, 2048, 0,  // h
         16384, 2048, 2048, 1, EPI_SILU, 0.f, nullptr, 0, 0, nullptr, nullptr);
    transpose_cvt<<<dim3(32, 64), 256, 0, stream>>>(W2, w8, 2048, 1024);  // -> [1024,2048]
    gemm(S1, 2048, 0, w8, 2048, 0, eb2 + e * 1024, nullptr, 0, routed, 1024, 0,
         16384, 1024, 2048, 1, EPI_ROUTED, 0.f, probs, e, (e > 0) ? 1 : 0, nullptr, nullptr);
  }

  // ---- phase D: gate ----
  transpose_cvt<<<dim3(32, 64), 256, 0, stream>>>(gw1, w8, 2048, 1024);  // first 2048 rows -> [1024,2048]
  anchor_term<<<4, 256, 0, stream>>>(anchor, gw1, 1024, 1024, anch);
  gemm(ne, 2048, 0, w8, 2048, 0, gb1, anch, 1024, gh, 1024, 0,
       16384, 1024, 2048, 1, EPI_SILU, 0.f, nullptr, 0, 0, nullptr, nullptr);
  transpose_cvt<<<dim3(32, 32), 256, 0, stream>>>(gw2, w8, 1024, 1024);
  gemm(gh, 1024, 0, w8, 1024, 0, gb2, nullptr, 0, g, 1024, 0,
       16384, 1024, 1024, 1, EPI_SIGMOID, 0.f, nullptr, 0, 0, nullptr, nullptr);

  // ---- phase E: out proj + residual ----
  cvt_bf16<<<4096, 256, 0, stream>>>(routed, routed_bf, 16777216);
  transpose_cvt<<<dim3(32, 32), 256, 0, stream>>>(ow, w8, 1024, 1024);
  gemm(routed_bf, 1024, 0, w8, 1024, 0, ob, nullptr, 0, out, 1024, 0,
       16384, 1024, 1024, 1, EPI_FINAL, 0.f, nullptr, 0, 0, X, g);
}

// Round 2
// 2139.790 us; speedup vs baseline: 1.4718x; 1.4155x over previous
//
#include <hip/hip_runtime.h>

typedef unsigned short u16;
typedef __bf16 bf16x8 __attribute__((ext_vector_type(8)));
typedef float f32x4 __attribute__((ext_vector_type(4)));

__device__ __forceinline__ float b2f(u16 u) {
  union { unsigned int i; float f; } x; x.i = ((unsigned int)u) << 16; return x.f;
}
__device__ __forceinline__ u16 f2b(float f) {
  union { float f; unsigned int i; } x; x.f = f;
  unsigned int r = (x.i + 0x7fffu + ((x.i >> 16) & 1u)) >> 16;
  return (u16)r;
}

__device__ __forceinline__ void async16(const void* g, void* l) {
  __builtin_amdgcn_global_load_lds((const __attribute__((address_space(1))) void*)g,
                                   (__attribute__((address_space(3))) void*)l, 16, 0, 0);
}

// Epilogue modes
#define EPI_BF16    0   // store bf16(v)
#define EPI_SILU    1   // store bf16(silu(v))
#define EPI_SIGMOID 2   // store bf16(sigmoid(v))
#define EPI_ROUTED  3   // f32 C [+]= rowscale[row*3+rs_off]*v
#define EPI_FINAL   4   // f32 C = X + G*v  (X f32, G bf16)
#define EPI_F32SC   5   // store f32 v*scale
// v = acc + bias[col] + bcast[(row>>11)*ldbc + col]

// C[M,N] = A[M,K] @ Bt[N,K]^T ; 128x128 tile, BK=32, 4 waves (2x2), 4x4 MFMA tiles/wave
// Double-buffered LDS: prefetch next K-step's tiles while computing current one.
__global__ __launch_bounds__(256) void gemm_bt(
    const u16* __restrict__ A, int lda, long long sA,
    const u16* __restrict__ B, int ldb, long long sB,
    const float* __restrict__ bias,
    const float* __restrict__ bcast, int ldbc,
    void* __restrict__ Cv, int ldc, long long sC,
    int M, int N, int K,
    int epi, float scale,
    const float* __restrict__ rowscale, int rs_off, int accum,
    const float* __restrict__ Xres, const u16* __restrict__ Gg)
{
  __shared__ u16 As[2][128 * 32];
  __shared__ u16 Bs[2][128 * 32];
  const int z = blockIdx.z;
  A += (long long)z * sA;
  B += (long long)z * sB;
  const int m0 = blockIdx.y * 128, n0 = blockIdx.x * 128;
  const int tid = threadIdx.x;
  const int lane = tid & 63, w = tid >> 6;
  const int wm = w >> 1, wn = w & 1;

  const int sr = lane >> 2;
  const int sc = (lane & 3) * 8;
  int ra0 = m0 + w * 16 + sr;      if (ra0 > M - 1) ra0 = M - 1;
  int ra1 = m0 + 64 + w * 16 + sr; if (ra1 > M - 1) ra1 = M - 1;
  int rb0 = n0 + w * 16 + sr;      if (rb0 > N - 1) rb0 = N - 1;
  int rb1 = n0 + 64 + w * 16 + sr; if (rb1 > N - 1) rb1 = N - 1;
  const u16* pa0 = A + (long long)ra0 * lda + sc;
  const u16* pa1 = A + (long long)ra1 * lda + sc;
  const u16* pb0 = B + (long long)rb0 * ldb + sc;
  const u16* pb1 = B + (long long)rb1 * ldb + sc;
  const int lw = w * 512;   // wave-uniform LDS chunk offset (u16 units)

  f32x4 acc[4][4] = {};

  const int kch = (lane >> 4) * 8;
  const int rr = lane & 15;

  // prologue: stage K-step 0 into buffer 0
  async16(pa0, &As[0][lw]);
  async16(pa1, &As[0][2048 + lw]);
  async16(pb0, &Bs[0][lw]);
  async16(pb1, &Bs[0][2048 + lw]);

  int cur = 0;
  for (int k0 = 0; k0 < K; k0 += 32) {
    // barrier: (a) drains vmcnt -> buf[cur] staged; (b) all waves done reading buf[cur^1]
    __syncthreads();
    const int kn = k0 + 32;
    if (kn < K) {
      const int nb = cur ^ 1;
      // issue next tile's loads NOW; they fly under the MFMAs below and are
      // drained by the next iteration's barrier (implicit vmcnt(0)).
      async16(pa0 + kn, &As[nb][lw]);
      async16(pa1 + kn, &As[nb][2048 + lw]);
      async16(pb0 + kn, &Bs[nb][lw]);
      async16(pb1 + kn, &Bs[nb][2048 + lw]);
    }
    bf16x8 af[4], bfr[4];
#pragma unroll
    for (int mi = 0; mi < 4; ++mi)
      af[mi] = *(const bf16x8*)(&As[cur][(wm * 64 + mi * 16 + rr) * 32 + kch]);
#pragma unroll
    for (int ni = 0; ni < 4; ++ni)
      bfr[ni] = *(const bf16x8*)(&Bs[cur][(wn * 64 + ni * 16 + rr) * 32 + kch]);
#pragma unroll
    for (int mi = 0; mi < 4; ++mi)
#pragma unroll
      for (int ni = 0; ni < 4; ++ni)
        acc[mi][ni] = __builtin_amdgcn_mfma_f32_16x16x32_bf16(af[mi], bfr[ni], acc[mi][ni], 0, 0, 0);
    cur ^= 1;
  }

  u16* Cb = (u16*)Cv;
  float* Cf = (float*)Cv;
#pragma unroll
  for (int ni = 0; ni < 4; ++ni) {
    int col = n0 + wn * 64 + ni * 16 + (lane & 15);
    if (col >= N) continue;
    float bv = bias ? bias[col] : 0.0f;
#pragma unroll
    for (int mi = 0; mi < 4; ++mi) {
#pragma unroll
      for (int r = 0; r < 4; ++r) {
        int row = m0 + wm * 64 + mi * 16 + (lane >> 4) * 4 + r;
        if (row >= M) continue;
        float v = acc[mi][ni][r] + bv;
        if (bcast) v += bcast[(row >> 11) * ldbc + col];
        long long cidx = (long long)z * sC + (long long)row * ldc + col;
        if (epi == EPI_BF16) {
          Cb[cidx] = f2b(v);
        } else if (epi == EPI_SILU) {
          Cb[cidx] = f2b(v / (1.0f + __expf(-v)));
        } else if (epi == EPI_SIGMOID) {
          Cb[cidx] = f2b(1.0f / (1.0f + __expf(-v)));
        } else if (epi == EPI_ROUTED) {
          float rs = rowscale[row * 3 + rs_off];
          if (accum) Cf[cidx] += rs * v; else Cf[cidx] = rs * v;
        } else if (epi == EPI_FINAL) {
          long long xi = (long long)row * ldc + col;
          Cf[cidx] = Xres[xi] + b2f(Gg[xi]) * v;
        } else { // EPI_F32SC
          Cf[cidx] = v * scale;
        }
      }
    }
  }
}

// out[c][r] = bf16(in[r][c]); reads first R rows of f32 in (row stride C). dims multiples of 32.
__global__ __launch_bounds__(256) void transpose_cvt(const float* __restrict__ in, u16* __restrict__ out, int R, int C) {
  __shared__ float tile[32][33];
  int c0 = blockIdx.x * 32, r0 = blockIdx.y * 32;
  int tx = threadIdx.x & 31, ty = threadIdx.x >> 5;
#pragma unroll
  for (int i = 0; i < 4; ++i) {
    int r = ty + i * 8;
    tile[r][tx] = in[(long long)(r0 + r) * C + c0 + tx];
  }
  __syncthreads();
#pragma unroll
  for (int i = 0; i < 4; ++i) {
    int r = ty + i * 8;
    out[(long long)(c0 + r) * R + r0 + tx] = f2b(tile[tx][r]);
  }
}

__global__ __launch_bounds__(256) void cvt_bf16(const float* __restrict__ in, u16* __restrict__ out, int n) {
  for (int i = blockIdx.x * 256 + threadIdx.x; i < n; i += gridDim.x * 256)
    out[i] = f2b(in[i]);
}

// LayerNorm over H=1024 (f32 in); writes bf16 nx into ne[:, 0:1024] (row stride 2048)
__global__ __launch_bounds__(256) void ln_kernel(const float* __restrict__ x, const float* __restrict__ gamma,
                                                 const float* __restrict__ beta, u16* __restrict__ ne) {
  int t = blockIdx.x;
  int tid = threadIdx.x;
  const float* xr = x + (long long)t * 1024;
  float v[4];
  float s = 0.f, sq = 0.f;
#pragma unroll
  for (int i = 0; i < 4; ++i) {
    v[i] = xr[tid * 4 + i];
    s += v[i]; sq += v[i] * v[i];
  }
#pragma unroll
  for (int d = 32; d; d >>= 1) { s += __shfl_xor(s, d, 64); sq += __shfl_xor(sq, d, 64); }
  __shared__ float ls[4], lq[4];
  int w = tid >> 6, lane = tid & 63;
  if (lane == 0) { ls[w] = s; lq[w] = sq; }
  __syncthreads();
  s = ls[0] + ls[1] + ls[2] + ls[3];
  sq = lq[0] + lq[1] + lq[2] + lq[3];
  float mean = s * (1.0f / 1024.0f);
  float var = sq * (1.0f / 1024.0f) - mean * mean;
  float rstd = rsqrtf(var + 1e-5f);
  long long base = (long long)t * 2048;
#pragma unroll
  for (int i = 0; i < 4; ++i) {
    int c = tid * 4 + i;
    ne[base + c] = f2b((v[i] - mean) * rstd * gamma[c] + beta[c]);
  }
}

// k-split anchor partials: partial[kc][b][n] = sum_{k in chunk kc} anchor[b,k]*W[(2048+k)*ldw+n]
// grid: (ceil(N/256), KC). KC chunks of (1024/KC) k's each.
#define ANCH_KC 32
__global__ __launch_bounds__(256) void anchor_partial(const float* __restrict__ anchor, const float* __restrict__ W,
                                                      int ldw, int N, float* __restrict__ partial) {
  int n = blockIdx.x * 256 + threadIdx.x;
  if (n >= N) return;
  const int kc = blockIdx.y;
  const int kper = 1024 / ANCH_KC;
  const int k0 = kc * kper;
  float acc[8] = {};
  for (int k = k0; k < k0 + kper; ++k) {
    float wv = W[(long long)(2048 + k) * ldw + n];
#pragma unroll
    for (int b = 0; b < 8; ++b) acc[b] += anchor[b * 1024 + k] * wv;
  }
#pragma unroll
  for (int b = 0; b < 8; ++b)
    partial[((long long)kc * 8 + b) * N + n] = acc[b];
}

// bc[b][n] = sum_kc partial[kc][b][n]
__global__ __launch_bounds__(256) void anchor_reduce(const float* __restrict__ partial, int N, float* __restrict__ bc) {
  int i = blockIdx.x * 256 + threadIdx.x;
  if (i >= 8 * N) return;
  float s = 0.f;
#pragma unroll 8
  for (int kc = 0; kc < ANCH_KC; ++kc) s += partial[(long long)kc * 8 * N + i];
  bc[i] = s;
}

// softmax over P=64 scores per token; one wave per token
__global__ __launch_bounds__(256) void attn_softmax(const float* __restrict__ scores, u16* __restrict__ weights) {
  int gid = blockIdx.x * 256 + threadIdx.x;
  int t = gid >> 6, lane = gid & 63;
  float sv = scores[(long long)t * 64 + lane];
  float m = sv;
#pragma unroll
  for (int d = 32; d; d >>= 1) m = fmaxf(m, __shfl_xor(m, d, 64));
  float e = __expf(sv - m);
  float sum = e;
#pragma unroll
  for (int d = 32; d; d >>= 1) sum += __shfl_xor(sum, d, 64);
  weights[(long long)t * 64 + lane] = f2b(e / sum);
}

// router: logits[e] = ne[t,:]@rW[0:2048,e] + anchor[b,:]@rW[2048:3072,e] + rb[e]; softmax E=3
__global__ __launch_bounds__(256) void router_kernel(const u16* __restrict__ ne, const float* __restrict__ anchor,
                                                     const float* __restrict__ rW, const float* __restrict__ rb,
                                                     float* __restrict__ probs) {
  int gid = blockIdx.x * 256 + threadIdx.x;
  int t = gid >> 6, lane = gid & 63;
  int b = t >> 11;
  const u16* cr = ne + (long long)t * 2048;
  const float* ar = anchor + (long long)b * 1024;
  float s0 = 0.f, s1 = 0.f, s2 = 0.f;
  for (int c = lane; c < 2048; c += 64) {
    float xv = b2f(cr[c]);
    s0 += xv * rW[c * 3 + 0];
    s1 += xv * rW[c * 3 + 1];
    s2 += xv * rW[c * 3 + 2];
  }
  for (int c = lane; c < 1024; c += 64) {
    float xv = ar[c];
    s0 += xv * rW[(2048 + c) * 3 + 0];
    s1 += xv * rW[(2048 + c) * 3 + 1];
    s2 += xv * rW[(2048 + c) * 3 + 2];
  }
#pragma unroll
  for (int d = 32; d; d >>= 1) {
    s0 += __shfl_xor(s0, d, 64);
    s1 += __shfl_xor(s1, d, 64);
    s2 += __shfl_xor(s2, d, 64);
  }
  s0 += rb[0]; s1 += rb[1]; s2 += rb[2];
  float m = fmaxf(s0, fmaxf(s1, s2));
  float e0 = __expf(s0 - m), e1 = __expf(s1 - m), e2 = __expf(s2 - m);
  float inv = 1.0f / (e0 + e1 + e2);
  if (lane == 0) {
    probs[(long long)t * 3 + 0] = e0 * inv;
    probs[(long long)t * 3 + 1] = e1 * inv;
    probs[(long long)t * 3 + 2] = e2 * inv;
  }
}

extern "C" void kernel_launch(void* const* d_in, const int* in_sizes, int n_in,
                              void* d_out, int out_size, void* d_ws, size_t ws_size,
                              hipStream_t stream) {
  const float* X      = (const float*)d_in[0];   // [16384,1024]
  const float* anchor = (const float*)d_in[1];   // [8,1024]
  const float* proto  = (const float*)d_in[2];   // [512,1024]
  const float* gamma  = (const float*)d_in[3];
  const float* beta   = (const float*)d_in[4];
  const float* Wq     = (const float*)d_in[5];
  const float* Wk     = (const float*)d_in[6];
  const float* Wv     = (const float*)d_in[7];
  const float* rW     = (const float*)d_in[8];   // [3072,3]
  const float* rb     = (const float*)d_in[9];
  const float* ew1    = (const float*)d_in[10];  // [3,3072,2048]
  const float* eb1    = (const float*)d_in[11];
  const float* ew2    = (const float*)d_in[12];  // [3,2048,1024]
  const float* eb2    = (const float*)d_in[13];
  const float* gw1    = (const float*)d_in[14];  // [3072,1024]
  const float* gb1    = (const float*)d_in[15];
  const float* gw2    = (const float*)d_in[16];  // [1024,1024]
  const float* gb2    = (const float*)d_in[17];
  const float* ow     = (const float*)d_in[18];  // [1024,1024]
  const float* ob     = (const float*)d_in[19];
  float* out = (float*)d_out;

  char* p = (char*)d_ws;
  size_t used = 0;
  auto alloc = [&](size_t bytes) {
    char* r = p; size_t a = (bytes + 255) & ~((size_t)255);
    p += a; used += a; return r;
  };
  u16* ne     = (u16*)alloc(16384ull * 2048 * 2);     // 64 MB [nx | evidence] bf16
  u16* S1     = (u16*)alloc(16384ull * 2048 * 2);     // 64 MB: q -> h -> gh|g -> routed_bf|g
  float* routed = (float*)alloc(16384ull * 1024 * 4); // 64 MB
  u16* w8     = (u16*)alloc(2048ull * 2048 * 2);      // 8 MB weight scratch (bf16)
  u16* proto_bf = (u16*)alloc(512ull * 1024 * 2);     // 1 MB
  u16* kbuf   = (u16*)alloc(512ull * 1024 * 2);
  u16* v_t    = (u16*)alloc(1024ull * 512 * 2);
  u16* wts    = (u16*)alloc(16384ull * 64 * 2);
  float* scores = (float*)alloc(16384ull * 64 * 4);
  float* probs  = (float*)alloc(16384ull * 3 * 4);
  float* anch   = (float*)alloc(8ull * 2048 * 4);
  float* anchp  = (float*)alloc((size_t)ANCH_KC * 8 * 2048 * 4);  // 2 MB k-split partials
  if (used > ws_size) return;  // clean diagnostic fail instead of GPU fault

  u16* gh = S1;                    // gate hidden [16384,1024]
  u16* g  = S1 + 16384ull * 1024;  // sigmoid gate [16384,1024]
  u16* routed_bf = S1;             // reuses gh region after g is computed

  auto gemm = [&](const u16* A, int lda, long long sA,
                  const u16* B, int ldb, long long sB,
                  const float* bias, const float* bcast, int ldbc,
                  void* C, int ldc, long long sC,
                  int M, int N, int K, int Z,
                  int epi, float scale, const float* rs, int rs_off, int accum,
                  const float* Xr, const u16* Gg) {
    dim3 grd((N + 127) / 128, (M + 127) / 128, Z);
    gemm_bt<<<grd, 256, 0, stream>>>(A, lda, sA, B, ldb, sB, bias, bcast, ldbc,
                                     C, ldc, sC, M, N, K, epi, scale, rs, rs_off, accum, Xr, Gg);
  };

  // anchor term: bc[b][n] = anchor[b,:] @ W[2048:3072, 0:N]  (f32, k-split for parallelism)
  auto anchor_term = [&](const float* W, int ldw, int N, float* bc) {
    anchor_partial<<<dim3((N + 255) / 256, ANCH_KC), 256, 0, stream>>>(anchor, W, ldw, N, anchp);
    anchor_reduce<<<(8 * N + 255) / 256, 256, 0, stream>>>(anchp, N, bc);
  };

  // ---- phase A: LN + attention ----
  ln_kernel<<<16384, 256, 0, stream>>>(X, gamma, beta, ne);
  cvt_bf16<<<512, 256, 0, stream>>>(proto, proto_bf, 512 * 1024);

  transpose_cvt<<<dim3(32, 32), 256, 0, stream>>>(Wk, w8, 1024, 1024);
  gemm(proto_bf, 1024, 0, w8, 1024, 0, nullptr, nullptr, 0, kbuf, 1024, 0,
       512, 1024, 1024, 1, EPI_BF16, 0.f, nullptr, 0, 0, nullptr, nullptr);

  transpose_cvt<<<dim3(32, 32), 256, 0, stream>>>(Wv, w8, 1024, 1024);
  // v_t[h][bp] = sum_k Wv^T[h][k] * proto[bp][k]
  gemm(w8, 1024, 0, proto_bf, 1024, 0, nullptr, nullptr, 0, v_t, 512, 0,
       1024, 512, 1024, 1, EPI_BF16, 0.f, nullptr, 0, 0, nullptr, nullptr);

  transpose_cvt<<<dim3(32, 32), 256, 0, stream>>>(Wq, w8, 1024, 1024);
  gemm(ne, 2048, 0, w8, 1024, 0, nullptr, nullptr, 0, S1, 1024, 0,   // q
       16384, 1024, 1024, 1, EPI_BF16, 0.f, nullptr, 0, 0, nullptr, nullptr);

  gemm(S1, 1024, 2048ll * 1024, kbuf, 1024, 64ll * 1024, nullptr, nullptr, 0,
       scores, 64, 2048ll * 64, 2048, 64, 1024, 8, EPI_F32SC, 0.03125f, nullptr, 0, 0, nullptr, nullptr);
  attn_softmax<<<4096, 256, 0, stream>>>(scores, wts);
  gemm(wts, 64, 2048ll * 64, v_t, 512, 64, nullptr, nullptr, 0,
       ne + 1024, 2048, 2048ll * 2048, 2048, 1024, 64, 8, EPI_BF16, 0.f, nullptr, 0, 0, nullptr, nullptr);

  // ---- phase B: router ----
  router_kernel<<<4096, 256, 0, stream>>>(ne, anchor, rW, rb, probs);

  // ---- phase C: experts ----
  for (int e = 0; e < 3; ++e) {
    const float* W1 = ew1 + (long long)e * 3072 * 2048;  // [3072,2048]
    const float* W2 = ew2 + (long long)e * 2048 * 1024;  // [2048,1024]
    transpose_cvt<<<dim3(64, 64), 256, 0, stream>>>(W1, w8, 2048, 2048);  // first 2048 rows -> [2048,2048]
    anchor_term(W1, 2048, 2048, anch);
    gemm(ne, 2048, 0, w8, 2048, 0, eb1 + e * 2048, anch, 2048, S1, 2048, 0,  // h
         16384, 2048, 2048, 1, EPI_SILU, 0.f, nullptr, 0, 0, nullptr, nullptr);
    transpose_cvt<<<dim3(32, 64), 256, 0, stream>>>(W2, w8, 2048, 1024);  // -> [1024,2048]
    gemm(S1, 2048, 0, w8, 2048, 0, eb2 + e * 1024, nullptr, 0, routed, 1024, 0,
         16384, 1024, 2048, 1, EPI_ROUTED, 0.f, probs, e, (e > 0) ? 1 : 0, nullptr, nullptr);
  }

  // ---- phase D: gate ----
  transpose_cvt<<<dim3(32, 64), 256, 0, stream>>>(gw1, w8, 2048, 1024);  // first 2048 rows -> [1024,2048]
  anchor_term(gw1, 1024, 1024, anch);
  gemm(ne, 2048, 0, w8, 2048, 0, gb1, anch, 1024, gh, 1024, 0,
       16384, 1024, 2048, 1, EPI_SILU, 0.f, nullptr, 0, 0, nullptr, nullptr);
  transpose_cvt<<<dim3(32, 32), 256, 0, stream>>>(gw2, w8, 1024, 1024);
  gemm(gh, 1024, 0, w8, 1024, 0, gb2, nullptr, 0, g, 1024, 0,
       16384, 1024, 1024, 1, EPI_SIGMOID, 0.f, nullptr, 0, 0, nullptr, nullptr);

  // ---- phase E: out proj + residual ----
  cvt_bf16<<<4096, 256, 0, stream>>>(routed, routed_bf, 16777216);
  transpose_cvt<<<dim3(32, 32), 256, 0, stream>>>(ow, w8, 1024, 1024);
  gemm(routed_bf, 1024, 0, w8, 1024, 0, ob, nullptr, 0, out, 1024, 0,
       16384, 1024, 1024, 1, EPI_FINAL, 0.f, nullptr, 0, 0, X, g);
}